// Round 1
// baseline (547.749 us; speedup 1.0000x reference)
//
#include <hip/hip_runtime.h>

#define D 256
#define SH 16
#define Ss 4
#define CH 256          // nodes per chunk (one block per chunk)
#define NT 64           // nodes per LDS tile
#define XS_STRIDE 272   // f16 per row (544 B, 16B-mult, bank-spread)
#define WB_STRIDE 80    // f16 per row (160 B)

typedef _Float16 half8 __attribute__((ext_vector_type(8)));
typedef _Float16 half4 __attribute__((ext_vector_type(4)));
typedef float f32x4 __attribute__((ext_vector_type(4)));

// workspace layout (bytes)
#define OFF_AF16   ((size_t)0)         // a_f16[16][256]            8192
#define OFF_CM     ((size_t)8192)      // CM[16] f32 (= -6*||a||)
#define OFF_Q      ((size_t)8448)      // q[4][256] f32             4096
#define OFF_DESC   ((size_t)12544)     // int nchunks (+pad16), int4 desc[<=1295]
#define OFF_SUMEXP ((size_t)33280)     // [256][16] f32             16384
#define OFF_ACC    ((size_t)49664)     // [256][16][256] f32        4194304
#define OFF_WVT    ((size_t)4243968)   // WvT[256][256]
#define OFF_WOT    ((size_t)4506112)   // WoT[256][256]
#define OFF_FC1T   ((size_t)4768256)   // fc1T[1024][256]
#define OFF_FC2T   ((size_t)5816832)   // fc2T[256][256]

// ---------- K0: q = seeds@WqT+bq (blocks 0..3), chunk descriptors (block 4) ----------
__global__ void k_prep(const float* __restrict__ seeds,
                       const float* __restrict__ inw,
                       const float* __restrict__ inb,
                       const int* __restrict__ counts,
                       char* __restrict__ ws) {
  int t = threadIdx.x;
  if (blockIdx.x < 4) {
    int s = blockIdx.x;
    __shared__ float sv[D];
    sv[t] = seeds[s * D + t];
    __syncthreads();
    const float4* wr = (const float4*)(inw + (size_t)t * D);  // Wq row t
    float acc = inb[t];
    #pragma unroll 8
    for (int j = 0; j < 64; j++) {
      float4 w4 = wr[j];
      acc += w4.x * sv[4*j] + w4.y * sv[4*j+1] + w4.z * sv[4*j+2] + w4.w * sv[4*j+3];
    }
    ((float*)(ws + OFF_Q))[s * D + t] = acc;
  } else {
    __shared__ int s1[256], s2[256];
    int cnt = counts[t];
    int nch = (cnt + CH - 1) / CH;
    s1[t] = cnt; s2[t] = nch;
    __syncthreads();
    for (int off = 1; off < 256; off <<= 1) {
      int a1 = (t >= off) ? s1[t - off] : 0;
      int a2 = (t >= off) ? s2[t - off] : 0;
      __syncthreads();
      s1[t] += a1; s2[t] += a2;
      __syncthreads();
    }
    int start = s1[t] - cnt, cb = s2[t] - nch;
    int4* desc = (int4*)(ws + OFF_DESC + 16);
    for (int j = 0; j < nch; j++) {
      int nn = cnt - j * CH; if (nn > CH) nn = CH;
      desc[cb + j] = make_int4(t, start + j * CH, nn, 0);
    }
    if (t == 255) *(int*)(ws + OFF_DESC) = s2[255];
  }
}

// ---------- K1: a[sh] = 0.125 * q_sh @ Wk_h ; CM[sh] = -6*||a|| ----------
__global__ void k_mk_a(const float* __restrict__ inw, char* __restrict__ ws) {
  int sh = blockIdx.x;             // s*4 + h
  int s = sh >> 2, h = sh & 3;
  int j = threadIdx.x;
  __shared__ float qh[64];
  __shared__ float red[256];
  if (j < 64) qh[j] = ((const float*)(ws + OFF_Q))[s * D + h * 64 + j];
  __syncthreads();
  const float* wk = inw + (size_t)(D + h * 64) * D;  // Wk rows
  float a = 0.f;
  #pragma unroll 8
  for (int d = 0; d < 64; d++) a += qh[d] * wk[(size_t)d * D + j];
  a *= 0.125f;
  ((_Float16*)(ws + OFF_AF16))[sh * D + j] = (_Float16)a;
  red[j] = a * a;
  __syncthreads();
  for (int st = 128; st > 0; st >>= 1) { if (j < st) red[j] += red[j + st]; __syncthreads(); }
  if (j == 0) ((float*)(ws + OFF_CM))[sh] = -6.0f * sqrtf(red[0]);
}

// ---------- K2: weight transposes (coalesced epilogue reads) ----------
__global__ void k_transpose(const float* __restrict__ inw, const float* __restrict__ ow,
                            const float* __restrict__ f1w, const float* __restrict__ f2w,
                            char* __restrict__ ws) {
  int b = blockIdx.x;
  const float* src; float* dst; int R, C, ti, tj;
  if (b < 64)       { src = inw + (size_t)512 * D; dst = (float*)(ws + OFF_WVT);  R = 256; C = 256;  int x = b;        tj = x / 8;  ti = x % 8; }
  else if (b < 128) { src = ow;                    dst = (float*)(ws + OFF_WOT);  R = 256; C = 256;  int x = b - 64;   tj = x / 8;  ti = x % 8; }
  else if (b < 192) { src = f2w;                   dst = (float*)(ws + OFF_FC2T); R = 256; C = 256;  int x = b - 128;  tj = x / 8;  ti = x % 8; }
  else              { src = f1w;                   dst = (float*)(ws + OFF_FC1T); R = 256; C = 1024; int x = b - 192;  tj = x / 8;  ti = x % 8; }
  __shared__ float tl[32][33];
  int tx = threadIdx.x & 31, ty = threadIdx.x >> 5;   // 32 x 8
  #pragma unroll
  for (int k = 0; k < 4; k++) {
    int r = ty + k * 8;
    tl[r][tx] = src[(size_t)(ti * 32 + r) * C + tj * 32 + tx];
  }
  __syncthreads();
  #pragma unroll
  for (int k = 0; k < 4; k++) {
    int r = ty + k * 8;
    dst[(size_t)(tj * 32 + r) * R + ti * 32 + tx] = tl[tx][r];
  }
}

// ---------- K3: main single-sweep attention pass ----------
__launch_bounds__(256, 4)
__global__ void k_main(const float* __restrict__ nf, char* __restrict__ ws) {
  int nchunks = *(const int*)(ws + OFF_DESC);
  if ((int)blockIdx.x >= nchunks) return;
  int4 dsc = ((const int4*)(ws + OFF_DESC + 16))[blockIdx.x];
  int g = dsc.x, start = dsc.y, cnt = dsc.z;

  __shared__ _Float16 xs[NT * XS_STRIDE];   // node tile, f16, padded rows
  __shared__ _Float16 wb[SH * WB_STRIDE];   // softmax weights [sh][node]

  int t = threadIdx.x;
  int lane = t & 63, wv = t >> 6;
  int col = lane & 15, q = lane >> 4;

  // persistent B-frags of a (score GEMM), 32 VGPRs
  const _Float16* af = (const _Float16*)(ws + OFF_AF16);
  half8 aw[8];
  #pragma unroll
  for (int kc = 0; kc < 8; kc++) aw[kc] = *(const half8*)(af + col * D + kc * 32 + q * 8);
  float cmv = ((const float*)(ws + OFF_CM))[col];

  f32x4 acc[4] = {{0,0,0,0},{0,0,0,0},{0,0,0,0},{0,0,0,0}};  // [sh(4 rows)] x d-slice, C-resident
  float dsum = 0.f;

  int ntile = (cnt + NT - 1) / NT;
  for (int tile = 0; tile < ntile; tile++) {
    // ---- stage 64 x 256 f32 -> f16 LDS (coalesced float4 reads) ----
    #pragma unroll 4
    for (int p = 0; p < 16; p++) {
      int flat = p * 256 + t;
      int row = flat >> 6, c4 = flat & 63;
      int nloc = tile * NT + row;
      float4 v = make_float4(0.f, 0.f, 0.f, 0.f);
      if (nloc < cnt) v = ((const float4*)(nf + (size_t)(start + nloc) * D))[c4];
      half4 hv;
      hv[0] = (_Float16)v.x; hv[1] = (_Float16)v.y; hv[2] = (_Float16)v.z; hv[3] = (_Float16)v.w;
      *(half4*)(xs + row * XS_STRIDE + c4 * 4) = hv;
    }
    __syncthreads();

    // ---- scores: S[16n x 16sh] per wave (wave w owns nodes w*16..+15) ----
    f32x4 sc = {0, 0, 0, 0};
    const _Float16* xrow = xs + (wv * 16 + col) * XS_STRIDE + q * 8;
    #pragma unroll
    for (int kc = 0; kc < 8; kc++) {
      half8 xa = *(const half8*)(xrow + kc * 32);
      sc = __builtin_amdgcn_mfma_f32_16x16x32_f16(xa, aw[kc], sc, 0, 0, 0);
    }
    #pragma unroll
    for (int r = 0; r < 4; r++) {
      int nloc = wv * 16 + q * 4 + r;
      float arg = fminf(sc[r] + cmv, 10.f);
      float wj = (tile * NT + nloc < cnt) ? __expf(arg) : 0.f;
      _Float16 wh = (_Float16)wj;
      dsum += (float)wh;                    // denominator consistent with f16 numerator
      wb[col * WB_STRIDE + nloc] = wh;
    }
    __syncthreads();

    // ---- accumulate: acc[16sh x 64d-slice per wave] += w^T @ X ----
    #pragma unroll
    for (int ks = 0; ks < 2; ks++) {
      half8 wa = *(const half8*)(wb + col * WB_STRIDE + ks * 32 + q * 8);
      #pragma unroll
      for (int dt = 0; dt < 4; dt++) {
        int dd = wv * 64 + dt * 16 + col;
        half8 xb;
        #pragma unroll
        for (int jj = 0; jj < 8; jj++) xb[jj] = xs[(ks * 32 + q * 8 + jj) * XS_STRIDE + dd];
        acc[dt] = __builtin_amdgcn_mfma_f32_16x16x32_f16(wa, xb, acc[dt], 0, 0, 0);
      }
    }
    __syncthreads();
  }

  // ---- chunk epilogue: denominators + weighted sums via device atomics ----
  dsum += __shfl_xor(dsum, 16);
  dsum += __shfl_xor(dsum, 32);
  if (q == 0) atomicAdd(((float*)(ws + OFF_SUMEXP)) + g * SH + col, dsum);
  float* accw = (float*)(ws + OFF_ACC);
  #pragma unroll
  for (int dt = 0; dt < 4; dt++)
    #pragma unroll
    for (int r = 0; r < 4; r++)
      atomicAdd(&accw[(size_t)(g * SH + q * 4 + r) * D + wv * 64 + dt * 16 + col], acc[dt][r]);
}

// ---------- K4: finalize (xbar -> Wv -> Wo -> fc1+gelu -> fc2), 2 graphs/block ----------
__global__ void k_final(const float* __restrict__ inb, const float* __restrict__ ob,
                        const float* __restrict__ f1b, const float* __restrict__ f2b,
                        const char* __restrict__ ws, float* __restrict__ out) {
  int t = threadIdx.x;
  int g0 = blockIdx.x * 2;
  const float* sume = (const float*)(ws + OFF_SUMEXP);
  const float* accw = (const float*)(ws + OFF_ACC);
  const float* WvT = (const float*)(ws + OFF_WVT);
  const float* WoT = (const float*)(ws + OFF_WOT);
  const float* F1T = (const float*)(ws + OFF_FC1T);
  const float* F2T = (const float*)(ws + OFF_FC2T);

  __shared__ float xb2[2][SH][D];
  __shared__ float cx2[2][Ss][D];
  __shared__ float fl2[2][1024];
  __shared__ float hh2[2][D];
  __shared__ float inv[32];

  if (t < 32) inv[t] = 1.0f / sume[(g0 + (t >> 4)) * SH + (t & 15)];
  __syncthreads();
  for (int e = t; e < 2 * SH * D; e += 256) {
    int gg = e >> 12, sh = (e >> 8) & 15, d = e & 255;
    xb2[gg][sh][d] = accw[(size_t)(g0 + gg) * SH * D + sh * D + d] * inv[gg * 16 + sh];
  }
  __syncthreads();

  {  // ctx = Wv_h @ xbar + bv
    float ca[2][4] = {{0,0,0,0},{0,0,0,0}};
    int h = t >> 6;
    for (int d = 0; d < D; d++) {
      float wvd = WvT[(size_t)d * D + t];
      #pragma unroll
      for (int gg = 0; gg < 2; gg++)
        #pragma unroll
        for (int s = 0; s < 4; s++)
          ca[gg][s] += wvd * xb2[gg][s * 4 + h][d];
    }
    float bv = inb[2 * D + t];
    #pragma unroll
    for (int gg = 0; gg < 2; gg++)
      #pragma unroll
      for (int s = 0; s < 4; s++) cx2[gg][s][t] = ca[gg][s] + bv;
  }
  __syncthreads();
  {  // attended = Wo @ ctx + bo  -> flat
    float aa[2][4] = {{0,0,0,0},{0,0,0,0}};
    for (int d = 0; d < D; d++) {
      float wod = WoT[(size_t)d * D + t];
      #pragma unroll
      for (int gg = 0; gg < 2; gg++)
        #pragma unroll
        for (int s = 0; s < 4; s++)
          aa[gg][s] += wod * cx2[gg][s][d];
    }
    float bo = ob[t];
    #pragma unroll
    for (int gg = 0; gg < 2; gg++)
      #pragma unroll
      for (int s = 0; s < 4; s++) fl2[gg][s * D + t] = aa[gg][s] + bo;
  }
  __syncthreads();
  {  // h = gelu(fc1 @ flat + b)
    float f1[2] = {0, 0};
    for (int k = 0; k < 1024; k++) {
      float w1 = F1T[(size_t)k * D + t];
      f1[0] += w1 * fl2[0][k];
      f1[1] += w1 * fl2[1][k];
    }
    #pragma unroll
    for (int gg = 0; gg < 2; gg++) {
      float x = f1[gg] + f1b[t];
      hh2[gg][t] = 0.5f * x * (1.0f + erff(x * 0.70710678118654752f));
    }
  }
  __syncthreads();
  {  // out = fc2 @ h + b
    float f2[2] = {0, 0};
    for (int d = 0; d < D; d++) {
      float w2 = F2T[(size_t)d * D + t];
      f2[0] += w2 * hh2[0][d];
      f2[1] += w2 * hh2[1][d];
    }
    #pragma unroll
    for (int gg = 0; gg < 2; gg++) out[(size_t)(g0 + gg) * D + t] = f2[gg] + f2b[t];
  }
}

extern "C" void kernel_launch(void* const* d_in, const int* in_sizes, int n_in,
                              void* d_out, int out_size, void* d_ws, size_t ws_size,
                              hipStream_t stream) {
  const float* nf    = (const float*)d_in[0];
  const int*   cnts  = (const int*)d_in[1];
  const float* seeds = (const float*)d_in[2];
  const float* inw   = (const float*)d_in[3];
  const float* inb   = (const float*)d_in[4];
  const float* ow    = (const float*)d_in[5];
  const float* obv   = (const float*)d_in[6];
  const float* f1w   = (const float*)d_in[7];
  const float* f1b   = (const float*)d_in[8];
  const float* f2w   = (const float*)d_in[9];
  const float* f2b   = (const float*)d_in[10];
  char* ws = (char*)d_ws;
  float* out = (float*)d_out;
  int N = in_sizes[0] / D;

  hipMemsetAsync(ws + OFF_SUMEXP, 0, (size_t)16384 + 4194304, stream);   // sumexp + acc
  k_prep<<<5, 256, 0, stream>>>(seeds, inw, inb, cnts, ws);
  k_mk_a<<<16, 256, 0, stream>>>(inw, ws);
  k_transpose<<<448, 256, 0, stream>>>(inw, ow, f1w, f2w, ws);
  int maxc = (N + CH - 1) / CH + 256;
  k_main<<<maxc, 256, 0, stream>>>(nf, ws);
  k_final<<<128, 256, 0, stream>>>(inb, obv, f1b, f2b, ws, out);
}